// Round 1
// baseline (211.001 us; speedup 1.0000x reference)
//
#include <hip/hip_runtime.h>
#include <stdint.h>

// ---------------------------------------------------------------------------
// TimeCondAttention on MI355X (gfx950)
// B=2, N=2048, DIM=512, H=8, DH=64, TIME_DIM=512
// Pipeline: prep(bf16 weights) -> time GEMV -> LN+FiLM+mask -> q/kv GEMMs
//           -> flash attention (bias streamed once) -> split-bf16 out proj
// ---------------------------------------------------------------------------

using s16x8 = __attribute__((ext_vector_type(8))) short;
using f32x4 = __attribute__((ext_vector_type(4))) float;

#define EPSV 1e-5f
#define NEGV 1e6f

__device__ __forceinline__ unsigned short f2bf(float f) {
    unsigned int u = __float_as_uint(f);
    u += 0x7FFFu + ((u >> 16) & 1u);   // RNE (inputs finite)
    return (unsigned short)(u >> 16);
}
__device__ __forceinline__ float bf2f(unsigned short s) {
    return __uint_as_float((unsigned int)s << 16);
}

__device__ __forceinline__ void gl_lds16(const void* g, void* l) {
    __builtin_amdgcn_global_load_lds((const __attribute__((address_space(1))) void*)g,
                                     (__attribute__((address_space(3))) void*)l, 16, 0, 0);
}

__device__ __forceinline__ f32x4 mfma_bf16(s16x8 a, s16x8 b, f32x4 c) {
    return __builtin_amdgcn_mfma_f32_16x16x32_bf16(a, b, c, 0, 0, 0);
}

// ---------------- K0: weight conversion (w_q, w_kv bf16; w_out hi/lo split) --
__global__ void k_prep(const float* __restrict__ w_q, const float* __restrict__ w_kv,
                       const float* __restrict__ w_out,
                       unsigned short* __restrict__ wq, unsigned short* __restrict__ wkv,
                       unsigned short* __restrict__ wo_h, unsigned short* __restrict__ wo_l) {
    int idx = blockIdx.x * 256 + threadIdx.x;         // total 1,048,576 exactly
    if (idx < 262144) {
        wq[idx] = f2bf(w_q[idx]);
    } else if (idx < 786432) {
        int i = idx - 262144;
        wkv[i] = f2bf(w_kv[i]);
    } else {
        int i = idx - 786432;
        float v = w_out[i];
        unsigned short h = f2bf(v);
        wo_h[i] = h;
        wo_l[i] = f2bf(v - bf2f(h));
    }
}

// ---------------- K1: t = silu(time) @ w_time.T + b_time  ([2][1024] f32) ----
__global__ void k_time(const float* __restrict__ timev, const float* __restrict__ w_time,
                       const float* __restrict__ b_time, float* __restrict__ tc) {
    int wid = threadIdx.x >> 6, lane = threadIdx.x & 63;
    int b = blockIdx.x >> 8;
    int j = (blockIdx.x & 255) * 4 + wid;             // 0..1023
    const float* tv = timev + b * 512;
    const float* wr = w_time + (size_t)j * 512;
    float acc = 0.f;
#pragma unroll
    for (int i = 0; i < 8; ++i) {
        int k = i * 64 + lane;
        float t = tv[k];
        float s = t / (1.f + __expf(-t));             // silu
        acc += s * wr[k];
    }
#pragma unroll
    for (int m = 32; m >= 1; m >>= 1) acc += __shfl_xor(acc, m);
    if (lane == 0) tc[b * 1024 + j] = acc + b_time[j];
}

// ---------------- K2: LayerNorm + FiLM + seq_mask -> xn(bf16); x -> bf16 -----
__global__ void k_lnfilm(const float* __restrict__ x, const float* __restrict__ gamma,
                         const float* __restrict__ seq_mask, const float* __restrict__ tc,
                         unsigned short* __restrict__ xbf, unsigned short* __restrict__ xnbf) {
    int row = blockIdx.x;                             // b*2048 + n
    int b = row >> 11;
    int tid = threadIdx.x, wid = tid >> 6, lane = tid & 63;
    float2 xv = *(const float2*)(x + (size_t)row * 512 + tid * 2);
    float s = xv.x + xv.y;
    float sq = xv.x * xv.x + xv.y * xv.y;
#pragma unroll
    for (int m = 32; m >= 1; m >>= 1) { s += __shfl_xor(s, m); sq += __shfl_xor(sq, m); }
    __shared__ float red[8];
    if (lane == 0) { red[wid] = s; red[wid + 4] = sq; }
    __syncthreads();
    float ts = red[0] + red[1] + red[2] + red[3];
    float tq = red[4] + red[5] + red[6] + red[7];
    float mu = ts * (1.f / 512.f);
    float var = tq * (1.f / 512.f) - mu * mu;
    float rs = rsqrtf(var + EPSV);
    float qm = seq_mask[row];
    int j = tid * 2;
    const float* scb = tc + b * 1024;
    float o0 = ((xv.x - mu) * rs * gamma[j])     * (scb[j] + 1.f)     + scb[j + 512];
    float o1 = ((xv.y - mu) * rs * gamma[j + 1]) * (scb[j + 1] + 1.f) + scb[j + 513];
    size_t base = (size_t)row * 512 + j;
    xnbf[base]     = f2bf(o0 * qm);
    xnbf[base + 1] = f2bf(o1 * qm);
    xbf[base]      = f2bf(xv.x);
    xbf[base + 1]  = f2bf(xv.y);
}

// ---------------- K3: bf16 GEMM C = A[M,512] * W[Nout,512]^T, scatter epi ----
// EPI 0: q-proj (scale 0.125, layout [b,h,n,d]); EPI 1: kv-proj (k/v split)
template<int EPI>
__launch_bounds__(256)
__global__ void k_gemm(const unsigned short* __restrict__ A, const unsigned short* __restrict__ W,
                       unsigned short* __restrict__ o0, unsigned short* __restrict__ o1) {
    __shared__ unsigned short a_t[128 * 64];
    __shared__ unsigned short b_t[128 * 64];
    int tid = threadIdx.x, lane = tid & 63, wid = tid >> 6;
    int lc = lane & 15, lq = lane >> 4;
    int wr = wid >> 1, wc = wid & 1;
    int m0 = blockIdx.x * 128, n0 = blockIdx.y * 128;
    f32x4 acc[4][4];
#pragma unroll
    for (int i = 0; i < 4; ++i)
#pragma unroll
        for (int jn = 0; jn < 4; ++jn)
#pragma unroll
            for (int e = 0; e < 4; ++e) acc[i][jn][e] = 0.f;
    const unsigned short* Ab = A + (size_t)m0 * 512;
    const unsigned short* Wb = W + (size_t)n0 * 512;
    int wbase = wid * 64;
    for (int kt = 0; kt < 8; ++kt) {
        __syncthreads();
        // stage 128x64 bf16 tiles; XOR-swizzled source so swizzled reads work
#pragma unroll
        for (int i = 0; i < 4; ++i) {
            int p = i * 256 + wbase + lane;
            int row = p >> 3, ls = (p & 7) ^ (row & 7);
            gl_lds16(Ab + (size_t)row * 512 + kt * 64 + ls * 8, a_t + (i * 256 + wbase) * 8);
            gl_lds16(Wb + (size_t)row * 512 + kt * 64 + ls * 8, b_t + (i * 256 + wbase) * 8);
        }
        __syncthreads();
        s16x8 af[4][2], bw[4][2];
        const char* ab = (const char*)a_t;
        const char* bb = (const char*)b_t;
#pragma unroll
        for (int mf = 0; mf < 4; ++mf) {
            int row = wr * 64 + mf * 16 + lc;
            int key = (row & 7) << 4;
            af[mf][0] = *(const s16x8*)(ab + row * 128 + ((lq * 16) ^ key));
            af[mf][1] = *(const s16x8*)(ab + row * 128 + ((64 + lq * 16) ^ key));
        }
#pragma unroll
        for (int nf = 0; nf < 4; ++nf) {
            int row = wc * 64 + nf * 16 + lc;
            int key = (row & 7) << 4;
            bw[nf][0] = *(const s16x8*)(bb + row * 128 + ((lq * 16) ^ key));
            bw[nf][1] = *(const s16x8*)(bb + row * 128 + ((64 + lq * 16) ^ key));
        }
#pragma unroll
        for (int mf = 0; mf < 4; ++mf)
#pragma unroll
            for (int nf = 0; nf < 4; ++nf) {
                acc[mf][nf] = mfma_bf16(af[mf][0], bw[nf][0], acc[mf][nf]);
                acc[mf][nf] = mfma_bf16(af[mf][1], bw[nf][1], acc[mf][nf]);
            }
    }
#pragma unroll
    for (int mf = 0; mf < 4; ++mf)
#pragma unroll
        for (int nf = 0; nf < 4; ++nf)
#pragma unroll
            for (int r = 0; r < 4; ++r) {
                int grow = m0 + wr * 64 + mf * 16 + lq * 4 + r;
                int gcol = n0 + wc * 64 + nf * 16 + lc;
                float v = acc[mf][nf][r];
                int b = grow >> 11, n = grow & 2047;
                if (EPI == 0) {
                    int h = gcol >> 6, d = gcol & 63;
                    o0[((size_t)((b * 8 + h) * 2048 + n)) * 64 + d] = f2bf(v * 0.125f);
                } else {
                    int jj = gcol & 511;
                    int h = jj >> 6, d = jj & 63;
                    unsigned short* dst = (gcol < 512) ? o0 : o1;
                    dst[((size_t)((b * 8 + h) * 2048 + n)) * 64 + d] = f2bf(v);
                }
            }
}

// ---------------- K4: flash attention, bias streamed once -------------------
__launch_bounds__(256)
__global__ void k_attn(const unsigned short* __restrict__ qg, const unsigned short* __restrict__ kg,
                       const unsigned short* __restrict__ vg, const float* __restrict__ bias,
                       const float* __restrict__ seq_mask,
                       unsigned short* __restrict__ ah, unsigned short* __restrict__ al) {
    __shared__ unsigned short k_lds[64 * 64];   // [key][d] swizzled
    __shared__ unsigned short v_lds[64 * 64];   // [d][key] swizzled (transposed)
    __shared__ unsigned short p_lds[4][32 * 64];
    int tid = threadIdx.x, lane = tid & 63, wid = tid >> 6;
    int lc = lane & 15, lq = lane >> 4;
    int bh = blockIdx.y, b = bh >> 3, h = bh & 7;
    int q0 = blockIdx.x * 128 + wid * 32;

    // Q fragments straight from global (rows are 128B, 16B-aligned chunks)
    s16x8 aq[2][2];
    const unsigned short* qbase = qg + ((size_t)bh * 2048 + q0) * 64;
#pragma unroll
    for (int mf = 0; mf < 2; ++mf)
#pragma unroll
        for (int ks = 0; ks < 2; ++ks)
            aq[mf][ks] = *(const s16x8*)(qbase + (mf * 16 + lc) * 64 + ks * 32 + lq * 8);

    float mst[2][4], lst[2][4], qm[2][4];
    f32x4 acc[2][4];
#pragma unroll
    for (int mf = 0; mf < 2; ++mf)
#pragma unroll
        for (int r = 0; r < 4; ++r) {
            mst[mf][r] = -1e30f; lst[mf][r] = 0.f;
            qm[mf][r] = seq_mask[b * 2048 + q0 + mf * 16 + lq * 4 + r];
        }
#pragma unroll
    for (int mf = 0; mf < 2; ++mf)
#pragma unroll
        for (int df = 0; df < 4; ++df)
#pragma unroll
            for (int e = 0; e < 4; ++e) acc[mf][df][e] = 0.f;

    const float* bias_b = bias + ((size_t)bh * 2048 + q0) * 2048;
    char* pw = (char*)(&p_lds[wid][0]);
    int wbase = wid * 64;

    for (int kt = 0; kt < 32; ++kt) {
        __syncthreads();
        // --- stage K tile (global_load_lds, source pre-swizzled) ---
        const unsigned short* kgl = kg + ((size_t)bh * 2048 + kt * 64) * 64;
#pragma unroll
        for (int i = 0; i < 2; ++i) {
            int p = i * 256 + wbase + lane;
            int row = p >> 3, ls = (p & 7) ^ (row & 7);
            gl_lds16(kgl + row * 64 + ls * 8, k_lds + (i * 256 + wbase) * 8);
        }
        // --- stage V transposed via registers (swizzled writes) ---
        const unsigned short* vgl = vg + ((size_t)bh * 2048 + kt * 64) * 64;
        char* vbp = (char*)v_lds;
#pragma unroll
        for (int i = 0; i < 2; ++i) {
            int c = i * 256 + tid;
            int jrow = c >> 3, d0 = (c & 7) * 8;
            s16x8 vv = *(const s16x8*)(vgl + jrow * 64 + d0);
#pragma unroll
            for (int e = 0; e < 8; ++e) {
                int d = d0 + e;
                *(short*)(vbp + d * 128 + ((jrow * 2) ^ ((d & 7) << 4))) = vv[e];
            }
        }
        __syncthreads();

        // --- S = Q K^T ---
        s16x8 bk[4][2];
        const char* kb = (const char*)k_lds;
#pragma unroll
        for (int nf = 0; nf < 4; ++nf) {
            int row = nf * 16 + lc;
            int key = (row & 7) << 4;
            bk[nf][0] = *(const s16x8*)(kb + row * 128 + ((lq * 16) ^ key));
            bk[nf][1] = *(const s16x8*)(kb + row * 128 + ((64 + lq * 16) ^ key));
        }
        f32x4 s[2][4];
#pragma unroll
        for (int mf = 0; mf < 2; ++mf)
#pragma unroll
            for (int nf = 0; nf < 4; ++nf) {
#pragma unroll
                for (int e = 0; e < 4; ++e) s[mf][nf][e] = 0.f;
                s[mf][nf] = mfma_bf16(aq[mf][0], bk[nf][0], s[mf][nf]);
                s[mf][nf] = mfma_bf16(aq[mf][1], bk[nf][1], s[mf][nf]);
            }

        // --- bias + mask + online softmax ---
        float km[4];
#pragma unroll
        for (int nf = 0; nf < 4; ++nf) km[nf] = seq_mask[b * 2048 + kt * 64 + nf * 16 + lc];
#pragma unroll
        for (int mf = 0; mf < 2; ++mf) {
            const float* brow = bias_b + (size_t)(mf * 16 + lq * 4) * 2048 + kt * 64;
            float rmax[4];
#pragma unroll
            for (int r = 0; r < 4; ++r) {
#pragma unroll
                for (int nf = 0; nf < 4; ++nf) {
                    float bv = brow[(size_t)r * 2048 + nf * 16 + lc];
                    s[mf][nf][r] = s[mf][nf][r] + bv - (1.f - qm[mf][r] * km[nf]) * NEGV;
                }
                float mx = fmaxf(fmaxf(s[mf][0][r], s[mf][1][r]), fmaxf(s[mf][2][r], s[mf][3][r]));
#pragma unroll
                for (int m = 1; m <= 8; m <<= 1) mx = fmaxf(mx, __shfl_xor(mx, m));
                rmax[r] = mx;
            }
#pragma unroll
            for (int r = 0; r < 4; ++r) {
                float mn = fmaxf(mst[mf][r], rmax[r]);
                float scl = __expf(mst[mf][r] - mn);
                mst[mf][r] = mn;
                lst[mf][r] *= scl;
#pragma unroll
                for (int df = 0; df < 4; ++df)
#pragma unroll
                    for (int e = 0; e < 4; ++e)
                        if (e == r) acc[mf][df][e] = acc[mf][df][e] * scl;
                float rsum = 0.f;
#pragma unroll
                for (int nf = 0; nf < 4; ++nf) {
                    float p = __expf(s[mf][nf][r] - mn);
                    s[mf][nf][r] = p;
                    rsum += p;
                }
#pragma unroll
                for (int m = 1; m <= 8; m <<= 1) rsum += __shfl_xor(rsum, m);
                lst[mf][r] += rsum;
            }
            // write P (bf16) to per-wave LDS region, swizzled
#pragma unroll
            for (int nf = 0; nf < 4; ++nf)
#pragma unroll
                for (int r = 0; r < 4; ++r) {
                    int prow = mf * 16 + lq * 4 + r;
                    int pcol = nf * 16 + lc;
                    *(unsigned short*)(pw + prow * 128 + ((pcol * 2) ^ ((prow & 7) << 4))) =
                        f2bf(s[mf][nf][r]);
                }
        }
        asm volatile("s_waitcnt lgkmcnt(0)" ::: "memory");  // wave-local P visibility

        // --- O += P V ---
        s16x8 ap[2][2], bv_[4][2];
#pragma unroll
        for (int mf = 0; mf < 2; ++mf) {
            int prow = mf * 16 + lc;
            int key = (prow & 7) << 4;
            ap[mf][0] = *(const s16x8*)(pw + prow * 128 + ((lq * 16) ^ key));
            ap[mf][1] = *(const s16x8*)(pw + prow * 128 + ((64 + lq * 16) ^ key));
        }
        const char* vbr = (const char*)v_lds;
#pragma unroll
        for (int df = 0; df < 4; ++df) {
            int row = df * 16 + lc;
            int key = (row & 7) << 4;
            bv_[df][0] = *(const s16x8*)(vbr + row * 128 + ((lq * 16) ^ key));
            bv_[df][1] = *(const s16x8*)(vbr + row * 128 + ((64 + lq * 16) ^ key));
        }
#pragma unroll
        for (int mf = 0; mf < 2; ++mf)
#pragma unroll
            for (int df = 0; df < 4; ++df) {
                acc[mf][df] = mfma_bf16(ap[mf][0], bv_[df][0], acc[mf][df]);
                acc[mf][df] = mfma_bf16(ap[mf][1], bv_[df][1], acc[mf][df]);
            }
    }

    // --- epilogue: normalized output, hi/lo bf16 split for precise out-proj ---
#pragma unroll
    for (int mf = 0; mf < 2; ++mf)
#pragma unroll
        for (int df = 0; df < 4; ++df)
#pragma unroll
            for (int r = 0; r < 4; ++r) {
                float o = acc[mf][df][r] / lst[mf][r];
                int n = q0 + mf * 16 + lq * 4 + r;
                int d = df * 16 + lc;
                size_t idx = ((size_t)(b * 2048 + n)) * 512 + h * 64 + d;
                unsigned short hi = f2bf(o);
                ah[idx] = hi;
                al[idx] = f2bf(o - bf2f(hi));
            }
}

// ---------------- K5: out = (Ah+Al)(Wh+Wl)^T * seq_mask  (3-term split) -----
__launch_bounds__(256)
__global__ void k_gemm_out(const unsigned short* __restrict__ Ah, const unsigned short* __restrict__ Al,
                           const unsigned short* __restrict__ Wh, const unsigned short* __restrict__ Wl,
                           const float* __restrict__ seq_mask, float* __restrict__ out) {
    __shared__ unsigned short ah_t[128 * 32], al_t[128 * 32], bh_t[128 * 32], bl_t[128 * 32];
    int tid = threadIdx.x, lane = tid & 63, wid = tid >> 6;
    int lc = lane & 15, lq = lane >> 4;
    int wr = wid >> 1, wc = wid & 1;
    int m0 = blockIdx.x * 128, n0 = blockIdx.y * 128;
    f32x4 acc[4][4];
#pragma unroll
    for (int i = 0; i < 4; ++i)
#pragma unroll
        for (int jn = 0; jn < 4; ++jn)
#pragma unroll
            for (int e = 0; e < 4; ++e) acc[i][jn][e] = 0.f;
    int wbase = wid * 64;
    for (int kt = 0; kt < 16; ++kt) {
        __syncthreads();
#pragma unroll
        for (int i = 0; i < 2; ++i) {
            int p = i * 256 + wbase + lane;
            int row = p >> 2, ls = (p & 3) ^ (row & 3);
            size_t asrc = (size_t)(m0 + row) * 512 + kt * 32 + ls * 8;
            size_t bsrc = (size_t)(n0 + row) * 512 + kt * 32 + ls * 8;
            int dst = (i * 256 + wbase) * 8;
            gl_lds16(Ah + asrc, ah_t + dst);
            gl_lds16(Al + asrc, al_t + dst);
            gl_lds16(Wh + bsrc, bh_t + dst);
            gl_lds16(Wl + bsrc, bl_t + dst);
        }
        __syncthreads();
        s16x8 fah[4], fal[4], fbh[4], fbl[4];
#pragma unroll
        for (int mf = 0; mf < 4; ++mf) {
            int row = wr * 64 + mf * 16 + lc;
            int off = row * 64 + ((lq * 16) ^ ((row & 3) << 4));
            fah[mf] = *(const s16x8*)((const char*)ah_t + off);
            fal[mf] = *(const s16x8*)((const char*)al_t + off);
        }
#pragma unroll
        for (int nf = 0; nf < 4; ++nf) {
            int row = wc * 64 + nf * 16 + lc;
            int off = row * 64 + ((lq * 16) ^ ((row & 3) << 4));
            fbh[nf] = *(const s16x8*)((const char*)bh_t + off);
            fbl[nf] = *(const s16x8*)((const char*)bl_t + off);
        }
#pragma unroll
        for (int mf = 0; mf < 4; ++mf)
#pragma unroll
            for (int nf = 0; nf < 4; ++nf) {
                acc[mf][nf] = mfma_bf16(fah[mf], fbh[nf], acc[mf][nf]);
                acc[mf][nf] = mfma_bf16(fah[mf], fbl[nf], acc[mf][nf]);
                acc[mf][nf] = mfma_bf16(fal[mf], fbh[nf], acc[mf][nf]);
            }
    }
#pragma unroll
    for (int mf = 0; mf < 4; ++mf)
#pragma unroll
        for (int nf = 0; nf < 4; ++nf)
#pragma unroll
            for (int r = 0; r < 4; ++r) {
                int grow = m0 + wr * 64 + mf * 16 + lq * 4 + r;
                int gcol = n0 + wc * 64 + nf * 16 + lc;
                out[(size_t)grow * 512 + gcol] = acc[mf][nf][r] * seq_mask[grow];
            }
}

// ---------------------------------------------------------------------------
extern "C" void kernel_launch(void* const* d_in, const int* in_sizes, int n_in,
                              void* d_out, int out_size, void* d_ws, size_t ws_size,
                              hipStream_t stream) {
    const float* x         = (const float*)d_in[0];
    const float* timev     = (const float*)d_in[1];
    const float* attn_bias = (const float*)d_in[2];
    const float* seq_mask  = (const float*)d_in[3];
    const float* gamma     = (const float*)d_in[4];
    const float* w_time    = (const float*)d_in[5];
    const float* b_time    = (const float*)d_in[6];
    const float* w_q       = (const float*)d_in[7];
    const float* w_kv      = (const float*)d_in[8];
    const float* w_out     = (const float*)d_in[9];
    float* out = (float*)d_out;

    char* ws = (char*)d_ws;
    size_t off = 0;
    auto alloc = [&](size_t bytes) {
        char* p = ws + off;
        off += (bytes + 255) & ~(size_t)255;
        return p;
    };
    float*          tc   = (float*)alloc(2048 * 4);
    unsigned short* wq   = (unsigned short*)alloc(262144 * 2);
    unsigned short* wkv  = (unsigned short*)alloc(524288 * 2);
    unsigned short* wo_h = (unsigned short*)alloc(262144 * 2);
    unsigned short* wo_l = (unsigned short*)alloc(262144 * 2);
    unsigned short* xbf  = (unsigned short*)alloc(2097152 * 2);
    unsigned short* xnbf = (unsigned short*)alloc(2097152 * 2);
    unsigned short* qb   = (unsigned short*)alloc(2097152 * 2);
    unsigned short* kb   = (unsigned short*)alloc(2097152 * 2);
    unsigned short* vb   = (unsigned short*)alloc(2097152 * 2);
    unsigned short* ahh  = (unsigned short*)alloc(2097152 * 2);
    unsigned short* all_ = (unsigned short*)alloc(2097152 * 2);

    k_prep<<<4096, 256, 0, stream>>>(w_q, w_kv, w_out, wq, wkv, wo_h, wo_l);
    k_time<<<512, 256, 0, stream>>>(timev, w_time, b_time, tc);
    k_lnfilm<<<4096, 256, 0, stream>>>(x, gamma, seq_mask, tc, xbf, xnbf);
    k_gemm<0><<<dim3(32, 4), 256, 0, stream>>>(xnbf, wq, qb, nullptr);
    k_gemm<1><<<dim3(32, 8), 256, 0, stream>>>(xbf, wkv, kb, vb);
    k_attn<<<dim3(16, 16), 256, 0, stream>>>(qb, kb, vb, attn_bias, seq_mask, ahh, all_);
    k_gemm_out<<<dim3(32, 4), 256, 0, stream>>>(ahh, all_, wo_h, wo_l, seq_mask, out);
}

// Round 2
// 184.184 us; speedup vs baseline: 1.1456x; 1.1456x over previous
//
#include <hip/hip_runtime.h>
#include <stdint.h>

// ---------------------------------------------------------------------------
// TimeCondAttention on MI355X (gfx950)
// B=2, N=2048, DIM=512, H=8, DH=64, TIME_DIM=512
// R2: k_attn rewritten as a bias-stream pipeline:
//   - 64 q-rows/block (4 waves x 16 rows), grid 32x16=512 -> 2 blocks/CU
//   - bias tile staged via global_load_lds (coalesced), XOR-swizzled
//   - double-buffered K/V/bias, 1 barrier per K-tile
//   - XCD-bijective block swizzle (2 bh per XCD -> K/V L2-resident)
// ---------------------------------------------------------------------------

using s16x8 = __attribute__((ext_vector_type(8))) short;
using f32x4 = __attribute__((ext_vector_type(4))) float;

#define EPSV 1e-5f
#define NEGV 1e6f

__device__ __forceinline__ unsigned short f2bf(float f) {
    unsigned int u = __float_as_uint(f);
    u += 0x7FFFu + ((u >> 16) & 1u);   // RNE (inputs finite)
    return (unsigned short)(u >> 16);
}
__device__ __forceinline__ float bf2f(unsigned short s) {
    return __uint_as_float((unsigned int)s << 16);
}

__device__ __forceinline__ void gl_lds16(const void* g, void* l) {
    __builtin_amdgcn_global_load_lds((const __attribute__((address_space(1))) void*)g,
                                     (__attribute__((address_space(3))) void*)l, 16, 0, 0);
}

__device__ __forceinline__ f32x4 mfma_bf16(s16x8 a, s16x8 b, f32x4 c) {
    return __builtin_amdgcn_mfma_f32_16x16x32_bf16(a, b, c, 0, 0, 0);
}

// ---------------- K0: weight conversion (w_q, w_kv bf16; w_out hi/lo split) --
__global__ void k_prep(const float* __restrict__ w_q, const float* __restrict__ w_kv,
                       const float* __restrict__ w_out,
                       unsigned short* __restrict__ wq, unsigned short* __restrict__ wkv,
                       unsigned short* __restrict__ wo_h, unsigned short* __restrict__ wo_l) {
    int idx = blockIdx.x * 256 + threadIdx.x;         // total 1,048,576 exactly
    if (idx < 262144) {
        wq[idx] = f2bf(w_q[idx]);
    } else if (idx < 786432) {
        int i = idx - 262144;
        wkv[i] = f2bf(w_kv[i]);
    } else {
        int i = idx - 786432;
        float v = w_out[i];
        unsigned short h = f2bf(v);
        wo_h[i] = h;
        wo_l[i] = f2bf(v - bf2f(h));
    }
}

// ---------------- K1: t = silu(time) @ w_time.T + b_time  ([2][1024] f32) ----
__global__ void k_time(const float* __restrict__ timev, const float* __restrict__ w_time,
                       const float* __restrict__ b_time, float* __restrict__ tc) {
    int wid = threadIdx.x >> 6, lane = threadIdx.x & 63;
    int b = blockIdx.x >> 8;
    int j = (blockIdx.x & 255) * 4 + wid;             // 0..1023
    const float* tv = timev + b * 512;
    const float* wr = w_time + (size_t)j * 512;
    float acc = 0.f;
#pragma unroll
    for (int i = 0; i < 8; ++i) {
        int k = i * 64 + lane;
        float t = tv[k];
        float s = t / (1.f + __expf(-t));             // silu
        acc += s * wr[k];
    }
#pragma unroll
    for (int m = 32; m >= 1; m >>= 1) acc += __shfl_xor(acc, m);
    if (lane == 0) tc[b * 1024 + j] = acc + b_time[j];
}

// ---------------- K2: LayerNorm + FiLM + seq_mask -> xn(bf16); x -> bf16 -----
__global__ void k_lnfilm(const float* __restrict__ x, const float* __restrict__ gamma,
                         const float* __restrict__ seq_mask, const float* __restrict__ tc,
                         unsigned short* __restrict__ xbf, unsigned short* __restrict__ xnbf) {
    int row = blockIdx.x;                             // b*2048 + n
    int b = row >> 11;
    int tid = threadIdx.x, wid = tid >> 6, lane = tid & 63;
    float2 xv = *(const float2*)(x + (size_t)row * 512 + tid * 2);
    float s = xv.x + xv.y;
    float sq = xv.x * xv.x + xv.y * xv.y;
#pragma unroll
    for (int m = 32; m >= 1; m >>= 1) { s += __shfl_xor(s, m); sq += __shfl_xor(sq, m); }
    __shared__ float red[8];
    if (lane == 0) { red[wid] = s; red[wid + 4] = sq; }
    __syncthreads();
    float ts = red[0] + red[1] + red[2] + red[3];
    float tq = red[4] + red[5] + red[6] + red[7];
    float mu = ts * (1.f / 512.f);
    float var = tq * (1.f / 512.f) - mu * mu;
    float rs = rsqrtf(var + EPSV);
    float qm = seq_mask[row];
    int j = tid * 2;
    const float* scb = tc + b * 1024;
    float o0 = ((xv.x - mu) * rs * gamma[j])     * (scb[j] + 1.f)     + scb[j + 512];
    float o1 = ((xv.y - mu) * rs * gamma[j + 1]) * (scb[j + 1] + 1.f) + scb[j + 513];
    size_t base = (size_t)row * 512 + j;
    xnbf[base]     = f2bf(o0 * qm);
    xnbf[base + 1] = f2bf(o1 * qm);
    xbf[base]      = f2bf(xv.x);
    xbf[base + 1]  = f2bf(xv.y);
}

// ---------------- K3: bf16 GEMM C = A[M,512] * W[Nout,512]^T, scatter epi ----
// EPI 0: q-proj (scale 0.125, layout [b,h,n,d]); EPI 1: kv-proj (k/v split)
template<int EPI>
__launch_bounds__(256)
__global__ void k_gemm(const unsigned short* __restrict__ A, const unsigned short* __restrict__ W,
                       unsigned short* __restrict__ o0, unsigned short* __restrict__ o1) {
    __shared__ unsigned short a_t[128 * 64];
    __shared__ unsigned short b_t[128 * 64];
    int tid = threadIdx.x, lane = tid & 63, wid = tid >> 6;
    int lc = lane & 15, lq = lane >> 4;
    int wr = wid >> 1, wc = wid & 1;
    int m0 = blockIdx.x * 128, n0 = blockIdx.y * 128;
    f32x4 acc[4][4];
#pragma unroll
    for (int i = 0; i < 4; ++i)
#pragma unroll
        for (int jn = 0; jn < 4; ++jn)
#pragma unroll
            for (int e = 0; e < 4; ++e) acc[i][jn][e] = 0.f;
    const unsigned short* Ab = A + (size_t)m0 * 512;
    const unsigned short* Wb = W + (size_t)n0 * 512;
    int wbase = wid * 64;
    for (int kt = 0; kt < 8; ++kt) {
        __syncthreads();
        // stage 128x64 bf16 tiles; XOR-swizzled source so swizzled reads work
#pragma unroll
        for (int i = 0; i < 4; ++i) {
            int p = i * 256 + wbase + lane;
            int row = p >> 3, ls = (p & 7) ^ (row & 7);
            gl_lds16(Ab + (size_t)row * 512 + kt * 64 + ls * 8, a_t + (i * 256 + wbase) * 8);
            gl_lds16(Wb + (size_t)row * 512 + kt * 64 + ls * 8, b_t + (i * 256 + wbase) * 8);
        }
        __syncthreads();
        s16x8 af[4][2], bw[4][2];
        const char* ab = (const char*)a_t;
        const char* bb = (const char*)b_t;
#pragma unroll
        for (int mf = 0; mf < 4; ++mf) {
            int row = wr * 64 + mf * 16 + lc;
            int key = (row & 7) << 4;
            af[mf][0] = *(const s16x8*)(ab + row * 128 + ((lq * 16) ^ key));
            af[mf][1] = *(const s16x8*)(ab + row * 128 + ((64 + lq * 16) ^ key));
        }
#pragma unroll
        for (int nf = 0; nf < 4; ++nf) {
            int row = wc * 64 + nf * 16 + lc;
            int key = (row & 7) << 4;
            bw[nf][0] = *(const s16x8*)(bb + row * 128 + ((lq * 16) ^ key));
            bw[nf][1] = *(const s16x8*)(bb + row * 128 + ((64 + lq * 16) ^ key));
        }
#pragma unroll
        for (int mf = 0; mf < 4; ++mf)
#pragma unroll
            for (int nf = 0; nf < 4; ++nf) {
                acc[mf][nf] = mfma_bf16(af[mf][0], bw[nf][0], acc[mf][nf]);
                acc[mf][nf] = mfma_bf16(af[mf][1], bw[nf][1], acc[mf][nf]);
            }
    }
#pragma unroll
    for (int mf = 0; mf < 4; ++mf)
#pragma unroll
        for (int nf = 0; nf < 4; ++nf)
#pragma unroll
            for (int r = 0; r < 4; ++r) {
                int grow = m0 + wr * 64 + mf * 16 + lq * 4 + r;
                int gcol = n0 + wc * 64 + nf * 16 + lc;
                float v = acc[mf][nf][r];
                int b = grow >> 11, n = grow & 2047;
                if (EPI == 0) {
                    int h = gcol >> 6, d = gcol & 63;
                    o0[((size_t)((b * 8 + h) * 2048 + n)) * 64 + d] = f2bf(v * 0.125f);
                } else {
                    int jj = gcol & 511;
                    int h = jj >> 6, d = jj & 63;
                    unsigned short* dst = (gcol < 512) ? o0 : o1;
                    dst[((size_t)((b * 8 + h) * 2048 + n)) * 64 + d] = f2bf(v);
                }
            }
}

// ---------------- K4: flash attention, bias streamed through LDS ------------
__launch_bounds__(256)
__global__ void k_attn(const unsigned short* __restrict__ qg, const unsigned short* __restrict__ kg,
                       const unsigned short* __restrict__ vg, const float* __restrict__ bias,
                       const float* __restrict__ seq_mask,
                       unsigned short* __restrict__ ah, unsigned short* __restrict__ al) {
    __shared__ unsigned short k_lds[2][64 * 64];   // [key][d] swizzled   (8KB x2)
    __shared__ unsigned short v_lds[2][64 * 64];   // [d][key] swizzled   (8KB x2)
    __shared__ float          b_lds[2][64 * 64];   // [q][key] swizzled   (16KB x2)
    __shared__ unsigned short p_lds[4][16 * 64];   // per-wave P          (2KB x4)

    int tid = threadIdx.x, lane = tid & 63, w = tid >> 6;
    int lc = lane & 15, lq = lane >> 4;

    // XCD-bijective swizzle: 512 blocks, each XCD owns 2 bh (K/V L2-resident)
    int lin = blockIdx.x + 32 * blockIdx.y;
    int vid = (lin & 7) * 64 + (lin >> 3);
    int xblk = vid & 31, bh = vid >> 5;
    int b = bh >> 3, h = bh & 7;
    int bq0 = xblk * 64;
    int q0 = bq0 + w * 16;

    // Q fragments straight from global
    s16x8 aq[2];
    const unsigned short* qbase = qg + ((size_t)bh * 2048 + q0) * 64;
#pragma unroll
    for (int ks = 0; ks < 2; ++ks)
        aq[ks] = *(const s16x8*)(qbase + lc * 64 + ks * 32 + lq * 8);

    float mst[4], lst[4], qm[4];
    f32x4 acc[4];
#pragma unroll
    for (int r = 0; r < 4; ++r) {
        mst[r] = -1e30f; lst[r] = 0.f;
        qm[r] = seq_mask[b * 2048 + q0 + lq * 4 + r];
    }
#pragma unroll
    for (int df = 0; df < 4; ++df)
#pragma unroll
        for (int e = 0; e < 4; ++e) acc[df][e] = 0.f;

    const unsigned short* kgl0 = kg + (size_t)bh * 2048 * 64;
    const unsigned short* vgl0 = vg + (size_t)bh * 2048 * 64;
    const float* bgl0 = bias + ((size_t)bh * 2048 + bq0 + w * 16) * 2048;
    char* pw = (char*)(&p_lds[w][0]);

    // --- staging helpers (dbuf) ---
    auto issue_kb = [&](int kt, int bi) {
        const unsigned short* kgl = kgl0 + (size_t)kt * 64 * 64;
#pragma unroll
        for (int i = 0; i < 2; ++i) {
            int off = w * 2048 + i * 1024 + lane * 16;     // byte in k tile
            int row = off >> 7;                             // 128B rows
            int cc = ((off >> 4) & 7) ^ (row & 7);
            gl_lds16(kgl + row * 64 + cc * 8, (char*)k_lds[bi] + w * 2048 + i * 1024);
        }
        const float* bgl = bgl0 + (size_t)kt * 64;
#pragma unroll
        for (int i = 0; i < 4; ++i) {
            int off = i * 1024 + lane * 16;                 // byte in wave's 4KB
            int row = off >> 8;                             // 256B rows (local 0..15)
            int cc = ((off >> 4) & 15) ^ (row & 7);
            gl_lds16(bgl + (size_t)row * 2048 + cc * 4, (char*)b_lds[bi] + w * 4096 + i * 1024);
        }
    };
    auto issue_v = [&](int kt, s16x8& v0, s16x8& v1) {
        const unsigned short* vgl = vgl0 + (size_t)kt * 64 * 64;
        int c0 = tid, c1 = 256 + tid;
        v0 = *(const s16x8*)(vgl + (c0 >> 3) * 64 + (c0 & 7) * 8);
        v1 = *(const s16x8*)(vgl + (c1 >> 3) * 64 + (c1 & 7) * 8);
    };
    auto commit_v = [&](int bi, s16x8 v0, s16x8 v1) {
        char* vbp = (char*)v_lds[bi];
#pragma unroll
        for (int i = 0; i < 2; ++i) {
            s16x8 vv = i ? v1 : v0;
            int c = i * 256 + tid;
            int jrow = c >> 3, d0 = (c & 7) * 8;
#pragma unroll
            for (int e = 0; e < 8; ++e) {
                int d = d0 + e;
                *(short*)(vbp + d * 128 + ((jrow * 2) ^ ((d & 7) << 4))) = vv[e];
            }
        }
    };

    // prologue: fill buffer 0
    {
        s16x8 v0, v1;
        issue_kb(0, 0);
        issue_v(0, v0, v1);
        commit_v(0, v0, v1);
    }
    __syncthreads();

    for (int kt = 0; kt < 32; ++kt) {
        int cur = kt & 1, nxt = cur ^ 1;
        s16x8 nv0, nv1;
        if (kt < 31) {                      // issue next tile early (latency hidden)
            issue_kb(kt + 1, nxt);
            issue_v(kt + 1, nv0, nv1);
        }

        // --- S = Q K^T ---
        s16x8 bk[4][2];
        const char* kb = (const char*)k_lds[cur];
#pragma unroll
        for (int nf = 0; nf < 4; ++nf) {
            int row = nf * 16 + lc;
            int key = (row & 7) << 4;
            bk[nf][0] = *(const s16x8*)(kb + row * 128 + ((lq * 16) ^ key));
            bk[nf][1] = *(const s16x8*)(kb + row * 128 + ((64 + lq * 16) ^ key));
        }
        f32x4 s[4];
#pragma unroll
        for (int nf = 0; nf < 4; ++nf) {
#pragma unroll
            for (int e = 0; e < 4; ++e) s[nf][e] = 0.f;
            s[nf] = mfma_bf16(aq[0], bk[nf][0], s[nf]);
            s[nf] = mfma_bf16(aq[1], bk[nf][1], s[nf]);
        }

        // --- bias (from LDS) + mask + online softmax ---
        const float* bw_ = (const float*)b_lds[cur] + w * 1024;
        float km[4];
#pragma unroll
        for (int nf = 0; nf < 4; ++nf) km[nf] = seq_mask[b * 2048 + kt * 64 + nf * 16 + lc];
        float rmax[4];
#pragma unroll
        for (int r = 0; r < 4; ++r) {
            int rl = lq * 4 + r;
            int rk = (rl & 7);
#pragma unroll
            for (int nf = 0; nf < 4; ++nf) {
                int col = nf * 16 + lc;
                float bv = bw_[rl * 64 + (((col >> 2) ^ rk) << 2) + (col & 3)];
                s[nf][r] = s[nf][r] + bv - (1.f - qm[r] * km[nf]) * NEGV;
            }
            float mx = fmaxf(fmaxf(s[0][r], s[1][r]), fmaxf(s[2][r], s[3][r]));
#pragma unroll
            for (int m = 1; m <= 8; m <<= 1) mx = fmaxf(mx, __shfl_xor(mx, m));
            rmax[r] = mx;
        }
#pragma unroll
        for (int r = 0; r < 4; ++r) {
            float mn = fmaxf(mst[r], rmax[r]);
            float scl = __expf(mst[r] - mn);
            mst[r] = mn;
            lst[r] *= scl;
#pragma unroll
            for (int df = 0; df < 4; ++df)
#pragma unroll
                for (int e = 0; e < 4; ++e)
                    if (e == r) acc[df][e] = acc[df][e] * scl;
            float rsum = 0.f;
#pragma unroll
            for (int nf = 0; nf < 4; ++nf) {
                float p = __expf(s[nf][r] - mn);
                s[nf][r] = p;
                rsum += p;
            }
#pragma unroll
            for (int m = 1; m <= 8; m <<= 1) rsum += __shfl_xor(rsum, m);
            lst[r] += rsum;
        }
        // write P (bf16) to per-wave LDS region, swizzled
#pragma unroll
        for (int nf = 0; nf < 4; ++nf)
#pragma unroll
            for (int r = 0; r < 4; ++r) {
                int prow = lq * 4 + r;
                int pcol = nf * 16 + lc;
                *(unsigned short*)(pw + prow * 128 + ((pcol * 2) ^ ((prow & 7) << 4))) =
                    f2bf(s[nf][r]);
            }
        asm volatile("s_waitcnt lgkmcnt(0)" ::: "memory");  // wave-local P visibility

        // --- O += P V ---
        s16x8 ap[2], bv_[4][2];
#pragma unroll
        for (int ks = 0; ks < 2; ++ks) {
            int key = (lc & 7) << 4;
            ap[ks] = *(const s16x8*)(pw + lc * 128 + (((ks * 4 + lq) << 4) ^ key));
        }
        const char* vbr = (const char*)v_lds[cur];
#pragma unroll
        for (int df = 0; df < 4; ++df) {
            int row = df * 16 + lc;
            int key = (row & 7) << 4;
            bv_[df][0] = *(const s16x8*)(vbr + row * 128 + ((lq * 16) ^ key));
            bv_[df][1] = *(const s16x8*)(vbr + row * 128 + ((64 + lq * 16) ^ key));
        }
#pragma unroll
        for (int df = 0; df < 4; ++df) {
            acc[df] = mfma_bf16(ap[0], bv_[df][0], acc[df]);
            acc[df] = mfma_bf16(ap[1], bv_[df][1], acc[df]);
        }

        if (kt < 31) commit_v(nxt, nv0, nv1);  // compiler waits vmcnt for nv regs
        __syncthreads();                        // drains vmcnt(0): buf[nxt] ready
    }

    // --- epilogue: normalized output, hi/lo bf16 split for precise out-proj ---
#pragma unroll
    for (int df = 0; df < 4; ++df)
#pragma unroll
        for (int r = 0; r < 4; ++r) {
            float o = acc[df][r] / lst[r];
            int n = q0 + lq * 4 + r;
            int d = df * 16 + lc;
            size_t idx = ((size_t)(b * 2048 + n)) * 512 + h * 64 + d;
            unsigned short hi = f2bf(o);
            ah[idx] = hi;
            al[idx] = f2bf(o - bf2f(hi));
        }
}

// ---------------- K5: out = (Ah+Al)(Wh+Wl)^T * seq_mask  (3-term split) -----
__launch_bounds__(256)
__global__ void k_gemm_out(const unsigned short* __restrict__ Ah, const unsigned short* __restrict__ Al,
                           const unsigned short* __restrict__ Wh, const unsigned short* __restrict__ Wl,
                           const float* __restrict__ seq_mask, float* __restrict__ out) {
    __shared__ unsigned short ah_t[128 * 32], al_t[128 * 32], bh_t[128 * 32], bl_t[128 * 32];
    int tid = threadIdx.x, lane = tid & 63, wid = tid >> 6;
    int lc = lane & 15, lq = lane >> 4;
    int wr = wid >> 1, wc = wid & 1;
    int m0 = blockIdx.x * 128, n0 = blockIdx.y * 128;
    f32x4 acc[4][4];
#pragma unroll
    for (int i = 0; i < 4; ++i)
#pragma unroll
        for (int jn = 0; jn < 4; ++jn)
#pragma unroll
            for (int e = 0; e < 4; ++e) acc[i][jn][e] = 0.f;
    int wbase = wid * 64;
    for (int kt = 0; kt < 16; ++kt) {
        __syncthreads();
#pragma unroll
        for (int i = 0; i < 2; ++i) {
            int p = i * 256 + wbase + lane;
            int row = p >> 2, ls = (p & 3) ^ (row & 3);
            size_t asrc = (size_t)(m0 + row) * 512 + kt * 32 + ls * 8;
            size_t bsrc = (size_t)(n0 + row) * 512 + kt * 32 + ls * 8;
            int dst = (i * 256 + wbase) * 8;
            gl_lds16(Ah + asrc, ah_t + dst);
            gl_lds16(Al + asrc, al_t + dst);
            gl_lds16(Wh + bsrc, bh_t + dst);
            gl_lds16(Wl + bsrc, bl_t + dst);
        }
        __syncthreads();
        s16x8 fah[4], fal[4], fbh[4], fbl[4];
#pragma unroll
        for (int mf = 0; mf < 4; ++mf) {
            int row = wr * 64 + mf * 16 + lc;
            int off = row * 64 + ((lq * 16) ^ ((row & 3) << 4));
            fah[mf] = *(const s16x8*)((const char*)ah_t + off);
            fal[mf] = *(const s16x8*)((const char*)al_t + off);
        }
#pragma unroll
        for (int nf = 0; nf < 4; ++nf) {
            int row = wc * 64 + nf * 16 + lc;
            int off = row * 64 + ((lq * 16) ^ ((row & 3) << 4));
            fbh[nf] = *(const s16x8*)((const char*)bh_t + off);
            fbl[nf] = *(const s16x8*)((const char*)bl_t + off);
        }
#pragma unroll
        for (int mf = 0; mf < 4; ++mf)
#pragma unroll
            for (int nf = 0; nf < 4; ++nf) {
                acc[mf][nf] = mfma_bf16(fah[mf], fbh[nf], acc[mf][nf]);
                acc[mf][nf] = mfma_bf16(fah[mf], fbl[nf], acc[mf][nf]);
                acc[mf][nf] = mfma_bf16(fal[mf], fbh[nf], acc[mf][nf]);
            }
    }
#pragma unroll
    for (int mf = 0; mf < 4; ++mf)
#pragma unroll
        for (int nf = 0; nf < 4; ++nf)
#pragma unroll
            for (int r = 0; r < 4; ++r) {
                int grow = m0 + wr * 64 + mf * 16 + lq * 4 + r;
                int gcol = n0 + wc * 64 + nf * 16 + lc;
                out[(size_t)grow * 512 + gcol] = acc[mf][nf][r] * seq_mask[grow];
            }
}

// ---------------------------------------------------------------------------
extern "C" void kernel_launch(void* const* d_in, const int* in_sizes, int n_in,
                              void* d_out, int out_size, void* d_ws, size_t ws_size,
                              hipStream_t stream) {
    const float* x         = (const float*)d_in[0];
    const float* timev     = (const float*)d_in[1];
    const float* attn_bias = (const float*)d_in[2];
    const float* seq_mask  = (const float*)d_in[3];
    const float* gamma     = (const float*)d_in[4];
    const float* w_time    = (const float*)d_in[5];
    const float* b_time    = (const float*)d_in[6];
    const float* w_q       = (const float*)d_in[7];
    const float* w_kv      = (const float*)d_in[8];
    const float* w_out     = (const float*)d_in[9];
    float* out = (float*)d_out;

    char* ws = (char*)d_ws;
    size_t off = 0;
    auto alloc = [&](size_t bytes) {
        char* p = ws + off;
        off += (bytes + 255) & ~(size_t)255;
        return p;
    };
    float*          tc   = (float*)alloc(2048 * 4);
    unsigned short* wq   = (unsigned short*)alloc(262144 * 2);
    unsigned short* wkv  = (unsigned short*)alloc(524288 * 2);
    unsigned short* wo_h = (unsigned short*)alloc(262144 * 2);
    unsigned short* wo_l = (unsigned short*)alloc(262144 * 2);
    unsigned short* xbf  = (unsigned short*)alloc(2097152 * 2);
    unsigned short* xnbf = (unsigned short*)alloc(2097152 * 2);
    unsigned short* qb   = (unsigned short*)alloc(2097152 * 2);
    unsigned short* kb   = (unsigned short*)alloc(2097152 * 2);
    unsigned short* vb   = (unsigned short*)alloc(2097152 * 2);
    unsigned short* ahh  = (unsigned short*)alloc(2097152 * 2);
    unsigned short* all_ = (unsigned short*)alloc(2097152 * 2);

    k_prep<<<4096, 256, 0, stream>>>(w_q, w_kv, w_out, wq, wkv, wo_h, wo_l);
    k_time<<<512, 256, 0, stream>>>(timev, w_time, b_time, tc);
    k_lnfilm<<<4096, 256, 0, stream>>>(x, gamma, seq_mask, tc, xbf, xnbf);
    k_gemm<0><<<dim3(32, 4), 256, 0, stream>>>(xnbf, wq, qb, nullptr);
    k_gemm<1><<<dim3(32, 8), 256, 0, stream>>>(xbf, wkv, kb, vb);
    k_attn<<<dim3(32, 16), 256, 0, stream>>>(qb, kb, vb, attn_bias, seq_mask, ahh, all_);
    k_gemm_out<<<dim3(32, 4), 256, 0, stream>>>(ahh, all_, wo_h, wo_l, seq_mask, out);
}

// Round 3
// 153.672 us; speedup vs baseline: 1.3731x; 1.1986x over previous
//
#include <hip/hip_runtime.h>
#include <stdint.h>

// ---------------------------------------------------------------------------
// TimeCondAttention on MI355X (gfx950)
// B=2, N=2048, DIM=512, H=8, DH=64, TIME_DIM=512
// R3: k_attn = flight-spanning pipeline (counted vmcnt + raw s_barrier):
//   - swapped QK^T (S^T): bias + key-mask land as per-lane float4 registers
//   - bias register ring depth 4 (loop unrolled x4, no rotation movs)
//   - K and pre-transposed V^T staged via global_load_lds into 4-slot rings
//   - exactly 12 vm-ops/iter; tail = s_waitcnt vmcnt(16) lgkmcnt(0); s_barrier
//   - V^T produced by kv-GEMM epilogue ([b,h,d,n]) -> no in-kernel transpose
// ---------------------------------------------------------------------------

using s16x8 = __attribute__((ext_vector_type(8))) short;
using f32x4 = __attribute__((ext_vector_type(4))) float;
using u16x4 = __attribute__((ext_vector_type(4))) unsigned short;

#define EPSV 1e-5f
#define NEGV 1e6f

__device__ __forceinline__ unsigned short f2bf(float f) {
    unsigned int u = __float_as_uint(f);
    u += 0x7FFFu + ((u >> 16) & 1u);   // RNE (inputs finite)
    return (unsigned short)(u >> 16);
}
__device__ __forceinline__ float bf2f(unsigned short s) {
    return __uint_as_float((unsigned int)s << 16);
}

__device__ __forceinline__ void gl_lds16(const void* g, void* l) {
    __builtin_amdgcn_global_load_lds((const __attribute__((address_space(1))) void*)g,
                                     (__attribute__((address_space(3))) void*)l, 16, 0, 0);
}

__device__ __forceinline__ f32x4 mfma_bf16(s16x8 a, s16x8 b, f32x4 c) {
    return __builtin_amdgcn_mfma_f32_16x16x32_bf16(a, b, c, 0, 0, 0);
}

// ---------------- K0: weight conversion (w_q, w_kv bf16; w_out hi/lo split) --
__global__ void k_prep(const float* __restrict__ w_q, const float* __restrict__ w_kv,
                       const float* __restrict__ w_out,
                       unsigned short* __restrict__ wq, unsigned short* __restrict__ wkv,
                       unsigned short* __restrict__ wo_h, unsigned short* __restrict__ wo_l) {
    int idx = blockIdx.x * 256 + threadIdx.x;         // total 1,048,576 exactly
    if (idx < 262144) {
        wq[idx] = f2bf(w_q[idx]);
    } else if (idx < 786432) {
        int i = idx - 262144;
        wkv[i] = f2bf(w_kv[i]);
    } else {
        int i = idx - 786432;
        float v = w_out[i];
        unsigned short h = f2bf(v);
        wo_h[i] = h;
        wo_l[i] = f2bf(v - bf2f(h));
    }
}

// ---------------- K1: t = silu(time) @ w_time.T + b_time  ([2][1024] f32) ----
__global__ void k_time(const float* __restrict__ timev, const float* __restrict__ w_time,
                       const float* __restrict__ b_time, float* __restrict__ tc) {
    int wid = threadIdx.x >> 6, lane = threadIdx.x & 63;
    int b = blockIdx.x >> 8;
    int j = (blockIdx.x & 255) * 4 + wid;             // 0..1023
    const float* tv = timev + b * 512;
    const float* wr = w_time + (size_t)j * 512;
    float acc = 0.f;
#pragma unroll
    for (int i = 0; i < 8; ++i) {
        int k = i * 64 + lane;
        float t = tv[k];
        float s = t / (1.f + __expf(-t));             // silu
        acc += s * wr[k];
    }
#pragma unroll
    for (int m = 32; m >= 1; m >>= 1) acc += __shfl_xor(acc, m);
    if (lane == 0) tc[b * 1024 + j] = acc + b_time[j];
}

// ---------------- K2: LayerNorm + FiLM + seq_mask -> xn(bf16); x -> bf16 -----
__global__ void k_lnfilm(const float* __restrict__ x, const float* __restrict__ gamma,
                         const float* __restrict__ seq_mask, const float* __restrict__ tc,
                         unsigned short* __restrict__ xbf, unsigned short* __restrict__ xnbf) {
    int row = blockIdx.x;                             // b*2048 + n
    int b = row >> 11;
    int tid = threadIdx.x, wid = tid >> 6, lane = tid & 63;
    float2 xv = *(const float2*)(x + (size_t)row * 512 + tid * 2);
    float s = xv.x + xv.y;
    float sq = xv.x * xv.x + xv.y * xv.y;
#pragma unroll
    for (int m = 32; m >= 1; m >>= 1) { s += __shfl_xor(s, m); sq += __shfl_xor(sq, m); }
    __shared__ float red[8];
    if (lane == 0) { red[wid] = s; red[wid + 4] = sq; }
    __syncthreads();
    float ts = red[0] + red[1] + red[2] + red[3];
    float tq = red[4] + red[5] + red[6] + red[7];
    float mu = ts * (1.f / 512.f);
    float var = tq * (1.f / 512.f) - mu * mu;
    float rs = rsqrtf(var + EPSV);
    float qm = seq_mask[row];
    int j = tid * 2;
    const float* scb = tc + b * 1024;
    float o0 = ((xv.x - mu) * rs * gamma[j])     * (scb[j] + 1.f)     + scb[j + 512];
    float o1 = ((xv.y - mu) * rs * gamma[j + 1]) * (scb[j + 1] + 1.f) + scb[j + 513];
    size_t base = (size_t)row * 512 + j;
    xnbf[base]     = f2bf(o0 * qm);
    xnbf[base + 1] = f2bf(o1 * qm);
    xbf[base]      = f2bf(xv.x);
    xbf[base + 1]  = f2bf(xv.y);
}

// ---------------- K3: bf16 GEMM C = A[M,512] * W[Nout,512]^T, scatter epi ----
// EPI 0: q-proj (scale 0.125, [b,h,n,d]); EPI 1: kv-proj (k: [b,h,n,d], v: [b,h,d,n])
template<int EPI>
__launch_bounds__(256)
__global__ void k_gemm(const unsigned short* __restrict__ A, const unsigned short* __restrict__ W,
                       unsigned short* __restrict__ o0, unsigned short* __restrict__ o1) {
    __shared__ unsigned short a_t[128 * 64];
    __shared__ unsigned short b_t[128 * 64];
    int tid = threadIdx.x, lane = tid & 63, wid = tid >> 6;
    int lc = lane & 15, lq = lane >> 4;
    int wr = wid >> 1, wc = wid & 1;
    int m0 = blockIdx.x * 128, n0 = blockIdx.y * 128;
    f32x4 acc[4][4];
#pragma unroll
    for (int i = 0; i < 4; ++i)
#pragma unroll
        for (int jn = 0; jn < 4; ++jn)
#pragma unroll
            for (int e = 0; e < 4; ++e) acc[i][jn][e] = 0.f;
    const unsigned short* Ab = A + (size_t)m0 * 512;
    const unsigned short* Wb = W + (size_t)n0 * 512;
    int wbase = wid * 64;
    for (int kt = 0; kt < 8; ++kt) {
        __syncthreads();
        // stage 128x64 bf16 tiles; XOR-swizzled source so swizzled reads work
#pragma unroll
        for (int i = 0; i < 4; ++i) {
            int p = i * 256 + wbase + lane;
            int row = p >> 3, ls = (p & 7) ^ (row & 7);
            gl_lds16(Ab + (size_t)row * 512 + kt * 64 + ls * 8, a_t + (i * 256 + wbase) * 8);
            gl_lds16(Wb + (size_t)row * 512 + kt * 64 + ls * 8, b_t + (i * 256 + wbase) * 8);
        }
        __syncthreads();
        s16x8 af[4][2], bw[4][2];
        const char* ab = (const char*)a_t;
        const char* bb = (const char*)b_t;
#pragma unroll
        for (int mf = 0; mf < 4; ++mf) {
            int row = wr * 64 + mf * 16 + lc;
            int key = (row & 7) << 4;
            af[mf][0] = *(const s16x8*)(ab + row * 128 + ((lq * 16) ^ key));
            af[mf][1] = *(const s16x8*)(ab + row * 128 + ((64 + lq * 16) ^ key));
        }
#pragma unroll
        for (int nf = 0; nf < 4; ++nf) {
            int row = wc * 64 + nf * 16 + lc;
            int key = (row & 7) << 4;
            bw[nf][0] = *(const s16x8*)(bb + row * 128 + ((lq * 16) ^ key));
            bw[nf][1] = *(const s16x8*)(bb + row * 128 + ((64 + lq * 16) ^ key));
        }
#pragma unroll
        for (int mf = 0; mf < 4; ++mf)
#pragma unroll
            for (int nf = 0; nf < 4; ++nf) {
                acc[mf][nf] = mfma_bf16(af[mf][0], bw[nf][0], acc[mf][nf]);
                acc[mf][nf] = mfma_bf16(af[mf][1], bw[nf][1], acc[mf][nf]);
            }
    }
#pragma unroll
    for (int mf = 0; mf < 4; ++mf)
#pragma unroll
        for (int nf = 0; nf < 4; ++nf)
#pragma unroll
            for (int r = 0; r < 4; ++r) {
                int grow = m0 + wr * 64 + mf * 16 + lq * 4 + r;
                int gcol = n0 + wc * 64 + nf * 16 + lc;
                float v = acc[mf][nf][r];
                int b = grow >> 11, n = grow & 2047;
                if (EPI == 0) {
                    int h = gcol >> 6, d = gcol & 63;
                    o0[((size_t)((b * 8 + h) * 2048 + n)) * 64 + d] = f2bf(v * 0.125f);
                } else {
                    int jj = gcol & 511;
                    int h = jj >> 6, d = jj & 63;
                    if (gcol < 512) {
                        o0[((size_t)((b * 8 + h) * 2048 + n)) * 64 + d] = f2bf(v);
                    } else {
                        // V stored transposed: [b,h,d,n]
                        o1[((size_t)((b * 8 + h) * 64 + d)) * 2048 + n] = f2bf(v);
                    }
                }
            }
}

// ---------------- K4: flash attention, flight-spanning bias stream ----------
__launch_bounds__(256)
__global__ void k_attn(const unsigned short* __restrict__ qg, const unsigned short* __restrict__ kg,
                       const unsigned short* __restrict__ vt, const float* __restrict__ bias,
                       const float* __restrict__ seq_mask,
                       unsigned short* __restrict__ ah, unsigned short* __restrict__ al) {
    __shared__ unsigned short k_ring[4][64 * 64];   // [key][d] swizzled, 8KB/slot
    __shared__ unsigned short v_ring[4][64 * 64];   // [d][key] swizzled, 8KB/slot
    __shared__ unsigned short p_lds[4][16 * 64];    // per-wave P, 2KB/wave

    int tid = threadIdx.x, lane = tid & 63, w = tid >> 6;
    int lc = lane & 15, lq = lane >> 4;

    // XCD-bijective swizzle: 512 blocks, each XCD owns 2 bh (K/V L2-resident)
    int lin = blockIdx.x + 32 * blockIdx.y;
    int vid = (lin & 7) * 64 + (lin >> 3);
    int xblk = vid & 31, bh = vid >> 5;
    int b = bh >> 3, h = bh & 7;
    int q0 = xblk * 64 + w * 16;

    // Q fragments (B-operand now): Q[q=lc][d-chunk]
    s16x8 aq[2];
    const unsigned short* qbase = qg + ((size_t)bh * 2048 + q0) * 64;
#pragma unroll
    for (int ks = 0; ks < 2; ++ks)
        aq[ks] = *(const s16x8*)(qbase + lc * 64 + ks * 32 + lq * 8);

    float qm = seq_mask[b * 2048 + q0 + lc];
    float mst = -1e30f, lst = 0.f;
    f32x4 acc[4];
#pragma unroll
    for (int df = 0; df < 4; ++df)
#pragma unroll
        for (int e = 0; e < 4; ++e) acc[df][e] = 0.f;

    const unsigned short* kgl0 = kg + (size_t)bh * 2048 * 64;
    const unsigned short* vt0 = vt + (size_t)bh * 64 * 2048;
    const float* bias_q = bias + ((size_t)bh * 2048 + q0 + lc) * 2048;  // per-lane row
    const float* smk = seq_mask + b * 2048;
    char* pw = (char*)(&p_lds[w][0]);
    int swz = (lc & 7) << 4;

    // staging: K tile (rows = keys, contiguous 128B) and V^T tile (rows = d, strided)
    auto issue_k = [&](int tile, int slot) {
#pragma unroll
        for (int i = 0; i < 2; ++i) {
            int off = w * 2048 + i * 1024 + lane * 16;
            int row = off >> 7;
            int cc = ((off >> 4) & 7) ^ (row & 7);
            gl_lds16(kgl0 + ((size_t)tile * 64 + row) * 64 + cc * 8,
                     (char*)k_ring[slot] + w * 2048 + i * 1024);
        }
    };
    auto issue_vt = [&](int tile, int slot) {
#pragma unroll
        for (int i = 0; i < 2; ++i) {
            int off = w * 2048 + i * 1024 + lane * 16;
            int row = off >> 7;
            int cc = ((off >> 4) & 7) ^ (row & 7);
            gl_lds16(vt0 + (size_t)row * 2048 + tile * 64 + cc * 8,
                     (char*)v_ring[slot] + w * 2048 + i * 1024);
        }
    };

    f32x4 br[4][4];   // bias register ring [slot][nf], all indices static

    // ---- prologue: KV(0), KV(1), bias(0..2); wait KV(0); barrier ----
    issue_k(0, 0); issue_vt(0, 0);
    issue_k(1, 1); issue_vt(1, 1);
    __builtin_amdgcn_sched_barrier(0);
#pragma unroll
    for (int s = 0; s < 3; ++s)
#pragma unroll
        for (int nf = 0; nf < 4; ++nf)
            br[s][nf] = *(const f32x4*)(bias_q + s * 64 + nf * 16 + lq * 4);
    __builtin_amdgcn_sched_barrier(0);
    asm volatile("s_waitcnt vmcnt(16)" ::: "memory");
    __builtin_amdgcn_s_barrier();
    __builtin_amdgcn_sched_barrier(0);

    for (int t = 0; t < 8; ++t) {
#pragma unroll
        for (int u = 0; u < 4; ++u) {
            const int kt = t * 4 + u;
            // ---- load phase: exactly 12 vm ops, order pinned ----
            f32x4 km[4];
#pragma unroll
            for (int nf = 0; nf < 4; ++nf)
                km[nf] = *(const f32x4*)(smk + kt * 64 + nf * 16 + lq * 4);
            __builtin_amdgcn_sched_barrier(0);
            {
                int tk = (kt + 2) & 31;
                issue_k(tk, (u + 2) & 3);
                issue_vt(tk, (u + 2) & 3);
            }
            __builtin_amdgcn_sched_barrier(0);
            {
                int bt = (kt + 3) & 31;
#pragma unroll
                for (int nf = 0; nf < 4; ++nf)
                    br[(u + 3) & 3][nf] = *(const f32x4*)(bias_q + bt * 64 + nf * 16 + lq * 4);
            }
            __builtin_amdgcn_sched_barrier(0);

            // ---- S^T = K Q^T (swapped operands) ----
            s16x8 bk[4][2];
            const char* kb = (const char*)k_ring[u];
#pragma unroll
            for (int nf = 0; nf < 4; ++nf) {
                int row = nf * 16 + lc;
                bk[nf][0] = *(const s16x8*)(kb + row * 128 + ((lq * 16) ^ swz));
                bk[nf][1] = *(const s16x8*)(kb + row * 128 + ((64 + lq * 16) ^ swz));
            }
            f32x4 s[4];
            __builtin_amdgcn_s_setprio(1);
#pragma unroll
            for (int nf = 0; nf < 4; ++nf) {
#pragma unroll
                for (int e = 0; e < 4; ++e) s[nf][e] = 0.f;
                s[nf] = mfma_bf16(bk[nf][0], aq[0], s[nf]);
                s[nf] = mfma_bf16(bk[nf][1], aq[1], s[nf]);
            }
            __builtin_amdgcn_s_setprio(0);

            // ---- bias + mask + online softmax (row = q = lc, lane-local) ----
#pragma unroll
            for (int nf = 0; nf < 4; ++nf)
                s[nf] = s[nf] + br[u][nf] + (km[nf] * qm - 1.f) * NEGV;
            f32x4 m4 = s[0];
#pragma unroll
            for (int nf = 1; nf < 4; ++nf)
#pragma unroll
                for (int e = 0; e < 4; ++e) m4[e] = fmaxf(m4[e], s[nf][e]);
            float mx = fmaxf(fmaxf(m4[0], m4[1]), fmaxf(m4[2], m4[3]));
            mx = fmaxf(mx, __shfl_xor(mx, 16));
            mx = fmaxf(mx, __shfl_xor(mx, 32));
            float mn = fmaxf(mst, mx);
            float scl = __expf(mst - mn);
            mst = mn;
            float rsum = 0.f;
#pragma unroll
            for (int nf = 0; nf < 4; ++nf) {
                f32x4 p;
#pragma unroll
                for (int e = 0; e < 4; ++e) { p[e] = __expf(s[nf][e] - mn); rsum += p[e]; }
                unsigned int w0 = ((unsigned)f2bf(p[1]) << 16) | f2bf(p[0]);
                unsigned int w1 = ((unsigned)f2bf(p[3]) << 16) | f2bf(p[2]);
                *(unsigned int*)(pw + lc * 128 + ((nf * 32 + lq * 8) ^ swz)) = w0;
                *(unsigned int*)(pw + lc * 128 + ((nf * 32 + lq * 8 + 4) ^ swz)) = w1;
            }
            rsum += __shfl_xor(rsum, 16);
            rsum += __shfl_xor(rsum, 32);
            lst = lst * scl + rsum;
#pragma unroll
            for (int df = 0; df < 4; ++df)
#pragma unroll
                for (int e = 0; e < 4; ++e) acc[df][e] *= scl;
            asm volatile("s_waitcnt lgkmcnt(0)" ::: "memory");  // P visible (wave-local)

            // ---- O^T += V^T P^T ----
            s16x8 ap[2], bv_[4][2];
#pragma unroll
            for (int ks = 0; ks < 2; ++ks)
                ap[ks] = *(const s16x8*)(pw + lc * 128 + ((ks * 64 + lq * 16) ^ swz));
            const char* vbr = (const char*)v_ring[u];
#pragma unroll
            for (int df = 0; df < 4; ++df) {
                int row = df * 16 + lc;
                int key = (row & 7) << 4;
                bv_[df][0] = *(const s16x8*)(vbr + row * 128 + ((lq * 16) ^ key));
                bv_[df][1] = *(const s16x8*)(vbr + row * 128 + ((64 + lq * 16) ^ key));
            }
            __builtin_amdgcn_s_setprio(1);
#pragma unroll
            for (int df = 0; df < 4; ++df) {
                acc[df] = mfma_bf16(bv_[df][0], ap[0], acc[df]);
                acc[df] = mfma_bf16(bv_[df][1], ap[1], acc[df]);
            }
            __builtin_amdgcn_s_setprio(0);

            // ---- tail: counted wait (KV(kt+1) done; bias keeps flying) ----
            asm volatile("s_waitcnt vmcnt(16) lgkmcnt(0)" ::: "memory");
            __builtin_amdgcn_s_barrier();
            __builtin_amdgcn_sched_barrier(0);
        }
    }

    // ---- epilogue: O[q=lc][d], hi/lo bf16 split for precise out-proj ----
    float inv = 1.f / lst;
    size_t rowb = ((size_t)(b * 2048 + q0 + lc)) * 512 + h * 64;
#pragma unroll
    for (int df = 0; df < 4; ++df) {
        u16x4 hi, lo;
#pragma unroll
        for (int r = 0; r < 4; ++r) {
            float o = acc[df][r] * inv;
            unsigned short hb = f2bf(o);
            hi[r] = hb;
            lo[r] = f2bf(o - bf2f(hb));
        }
        *(u16x4*)(ah + rowb + df * 16 + lq * 4) = hi;
        *(u16x4*)(al + rowb + df * 16 + lq * 4) = lo;
    }
}

// ---------------- K5: out = (Ah+Al)(Wh+Wl)^T * seq_mask  (3-term split) -----
__launch_bounds__(256)
__global__ void k_gemm_out(const unsigned short* __restrict__ Ah, const unsigned short* __restrict__ Al,
                           const unsigned short* __restrict__ Wh, const unsigned short* __restrict__ Wl,
                           const float* __restrict__ seq_mask, float* __restrict__ out) {
    __shared__ unsigned short ah_t[128 * 32], al_t[128 * 32], bh_t[128 * 32], bl_t[128 * 32];
    int tid = threadIdx.x, lane = tid & 63, wid = tid >> 6;
    int lc = lane & 15, lq = lane >> 4;
    int wr = wid >> 1, wc = wid & 1;
    int m0 = blockIdx.x * 128, n0 = blockIdx.y * 128;
    f32x4 acc[4][4];
#pragma unroll
    for (int i = 0; i < 4; ++i)
#pragma unroll
        for (int jn = 0; jn < 4; ++jn)
#pragma unroll
            for (int e = 0; e < 4; ++e) acc[i][jn][e] = 0.f;
    int wbase = wid * 64;
    for (int kt = 0; kt < 16; ++kt) {
        __syncthreads();
#pragma unroll
        for (int i = 0; i < 2; ++i) {
            int p = i * 256 + wbase + lane;
            int row = p >> 2, ls = (p & 3) ^ (row & 3);
            size_t asrc = (size_t)(m0 + row) * 512 + kt * 32 + ls * 8;
            size_t bsrc = (size_t)(n0 + row) * 512 + kt * 32 + ls * 8;
            int dst = (i * 256 + wbase) * 8;
            gl_lds16(Ah + asrc, ah_t + dst);
            gl_lds16(Al + asrc, al_t + dst);
            gl_lds16(Wh + bsrc, bh_t + dst);
            gl_lds16(Wl + bsrc, bl_t + dst);
        }
        __syncthreads();
        s16x8 fah[4], fal[4], fbh[4], fbl[4];
#pragma unroll
        for (int mf = 0; mf < 4; ++mf) {
            int row = wr * 64 + mf * 16 + lc;
            int off = row * 64 + ((lq * 16) ^ ((row & 3) << 4));
            fah[mf] = *(const s16x8*)((const char*)ah_t + off);
            fal[mf] = *(const s16x8*)((const char*)al_t + off);
        }
#pragma unroll
        for (int nf = 0; nf < 4; ++nf) {
            int row = wc * 64 + nf * 16 + lc;
            int off = row * 64 + ((lq * 16) ^ ((row & 3) << 4));
            fbh[nf] = *(const s16x8*)((const char*)bh_t + off);
            fbl[nf] = *(const s16x8*)((const char*)bl_t + off);
        }
#pragma unroll
        for (int mf = 0; mf < 4; ++mf)
#pragma unroll
            for (int nf = 0; nf < 4; ++nf) {
                acc[mf][nf] = mfma_bf16(fah[mf], fbh[nf], acc[mf][nf]);
                acc[mf][nf] = mfma_bf16(fah[mf], fbl[nf], acc[mf][nf]);
                acc[mf][nf] = mfma_bf16(fal[mf], fbh[nf], acc[mf][nf]);
            }
    }
#pragma unroll
    for (int mf = 0; mf < 4; ++mf)
#pragma unroll
        for (int nf = 0; nf < 4; ++nf)
#pragma unroll
            for (int r = 0; r < 4; ++r) {
                int grow = m0 + wr * 64 + mf * 16 + lq * 4 + r;
                int gcol = n0 + wc * 64 + nf * 16 + lc;
                out[(size_t)grow * 512 + gcol] = acc[mf][nf][r] * seq_mask[grow];
            }
}

// ---------------------------------------------------------------------------
extern "C" void kernel_launch(void* const* d_in, const int* in_sizes, int n_in,
                              void* d_out, int out_size, void* d_ws, size_t ws_size,
                              hipStream_t stream) {
    const float* x         = (const float*)d_in[0];
    const float* timev     = (const float*)d_in[1];
    const float* attn_bias = (const float*)d_in[2];
    const float* seq_mask  = (const float*)d_in[3];
    const float* gamma     = (const float*)d_in[4];
    const float* w_time    = (const float*)d_in[5];
    const float* b_time    = (const float*)d_in[6];
    const float* w_q       = (const float*)d_in[7];
    const float* w_kv      = (const float*)d_in[8];
    const float* w_out     = (const float*)d_in[9];
    float* out = (float*)d_out;

    char* ws = (char*)d_ws;
    size_t off = 0;
    auto alloc = [&](size_t bytes) {
        char* p = ws + off;
        off += (bytes + 255) & ~(size_t)255;
        return p;
    };
    float*          tc   = (float*)alloc(2048 * 4);
    unsigned short* wq   = (unsigned short*)alloc(262144 * 2);
    unsigned short* wkv  = (unsigned short*)alloc(524288 * 2);
    unsigned short* wo_h = (unsigned short*)alloc(262144 * 2);
    unsigned short* wo_l = (unsigned short*)alloc(262144 * 2);
    unsigned short* xbf  = (unsigned short*)alloc(2097152 * 2);
    unsigned short* xnbf = (unsigned short*)alloc(2097152 * 2);
    unsigned short* qb   = (unsigned short*)alloc(2097152 * 2);
    unsigned short* kb   = (unsigned short*)alloc(2097152 * 2);
    unsigned short* vtb  = (unsigned short*)alloc(2097152 * 2);
    unsigned short* ahh  = (unsigned short*)alloc(2097152 * 2);
    unsigned short* all_ = (unsigned short*)alloc(2097152 * 2);

    k_prep<<<4096, 256, 0, stream>>>(w_q, w_kv, w_out, wq, wkv, wo_h, wo_l);
    k_time<<<512, 256, 0, stream>>>(timev, w_time, b_time, tc);
    k_lnfilm<<<4096, 256, 0, stream>>>(x, gamma, seq_mask, tc, xbf, xnbf);
    k_gemm<0><<<dim3(32, 4), 256, 0, stream>>>(xnbf, wq, qb, nullptr);
    k_gemm<1><<<dim3(32, 8), 256, 0, stream>>>(xbf, wkv, kb, vtb);
    k_attn<<<dim3(32, 16), 256, 0, stream>>>(qb, kb, vtb, attn_bias, seq_mask, ahh, all_);
    k_gemm_out<<<dim3(32, 4), 256, 0, stream>>>(ahh, all_, wo_h, wo_l, seq_mask, out);
}